// Round 15
// baseline (29.470 us; speedup 1.0000x reference)
//
#include <hip/hip_runtime.h>

// TransformerBlockQuantum: B=16384, S=8, E=8, H=8 (dk=1), NW=8, FFN=512.
// R15: K1 = 2-lanes-per-token front (R11 layout + R14 kv-pack), 4096 blocks
//   x 64 thr -> 4096 waves (4/SIMD). Writes hh into d_out (scratch).
//   Blocks 0-63 also prepack MFMA fragments into d_ws.
// K2 = R13's FFN+LN2: 256 thr/4 waves, fragments LDS-staged, 32 tokens/wave.

typedef __fp16 half2v __attribute__((ext_vector_type(2)));
typedef __fp16 half4  __attribute__((ext_vector_type(4)));
typedef float  float4v __attribute__((ext_vector_type(4)));

// xor-1 partner exchange (float)
#define SWZ1(v) __int_as_float(__builtin_amdgcn_ds_swizzle(__float_as_int(v), (1 << 10) | 0x1F))
// xor-16 pair (float) for K2 epilogue
#define SWZ16(v) __int_as_float(__builtin_amdgcn_ds_swizzle(__float_as_int(v), (16 << 10) | 0x1F))
// j-gather on int: new_id5 = (id5 & 0b10001) | (j<<1)  [same parity+batch, token j]
#define SWZJI_(v, jlit) __builtin_amdgcn_ds_swizzle((v), ((jlit) << 6) | 0x11)
#define GATHERJ8(dst, src)                                      \
    do {                                                        \
        dst[0] = SWZJI_(src, 0); dst[1] = SWZJI_(src, 1);       \
        dst[2] = SWZJI_(src, 2); dst[3] = SWZJI_(src, 3);       \
        dst[4] = SWZJI_(src, 4); dst[5] = SWZJI_(src, 5);       \
        dst[6] = SWZJI_(src, 6); dst[7] = SWZJI_(src, 7);       \
    } while (0)

#define DOT4(a, vw) (fmaf((a)[3], (vw).w, fmaf((a)[2], (vw).z, fmaf((a)[1], (vw).y, (a)[0] * (vw).x))))

// ================= K1: 2-lane front (+ fragment pack in blocks 0-63) ==========
__global__ __launch_bounds__(64, 4) void tbq_front(
    const float* __restrict__ x,
    const float* __restrict__ ipw, const float* __restrict__ ipb,
    const float* __restrict__ opw, const float* __restrict__ opb,
    const float* __restrict__ rxa,
    const float* __restrict__ cw,  const float* __restrict__ cb,
    const float* __restrict__ g1,  const float* __restrict__ b1,
    const float* __restrict__ l1w, const float* __restrict__ l1b,
    const float* __restrict__ l2w,
    half4* __restrict__ a1ws, half4* __restrict__ a2ws,
    float* __restrict__ hhout)
{
    // ---- fragment pack (blocks 0-63: 4096 threads cover both arrays) ----
    if (blockIdx.x < 64) {
        int t = blockIdx.x * 64 + threadIdx.x;    // 0..4095
        int u = t & 2047;
        int nf = u >> 6, ll = u & 63;
        int mm = ll & 15, kk0 = (ll >> 4) * 4;
        half4 r;
        if (t < 2048) {
            int f = nf * 16 + mm;
            #pragma unroll
            for (int j = 0; j < 4; ++j) {
                int k = kk0 + j;
                float v = (k < 8) ? l1w[f * 8 + k] : ((k == 8) ? l1b[f] : 0.f);
                r[j] = (__fp16)v;
            }
            a1ws[nf * 64 + ll] = r;
        } else {
            #pragma unroll
            for (int j = 0; j < 4; ++j) {
                int k = kk0 + j;
                float v = (mm < 8) ? l2w[mm * 512 + nf * 16 + k] : 0.f;
                r[j] = (__fp16)v;
            }
            a2ws[nf * 64 + ll] = r;
        }
    }

    const int l    = threadIdx.x;
    const int p    = l & 1;                  // embed/head half
    const int t    = l >> 1;                 // token in wave (0..31)
    const int e0   = p * 4;
    const int tok  = blockIdx.x * 32 + t;
    const int base = tok * 8;
    const bool sel = (p == 0);

    // ---- x: own half + partner half ----
    float4 xo4 = *reinterpret_cast<const float4*>(x + base + e0);
    float xown[4] = {xo4.x, xo4.y, xo4.z, xo4.w};
    float xoth[4] = {SWZ1(xown[0]), SWZ1(xown[1]), SWZ1(xown[2]), SWZ1(xown[3])};
    float xlo[4], xhi[4];
    #pragma unroll
    for (int j = 0; j < 4; ++j) {
        xlo[j] = sel ? xown[j] : xoth[j];
        xhi[j] = sel ? xoth[j] : xown[j];
    }

    // ---- in_proj: own 4 rows of q, k, v ----
    const float4* ipw4 = reinterpret_cast<const float4*>(ipw);
    float q4[4], k4[4], v4[4];
    #pragma unroll
    for (int i = 0; i < 4; ++i) {
        int rq = e0 + i, rk = 8 + e0 + i, rv = 16 + e0 + i;
        float4 wl, wh;
        wl = ipw4[rq * 2]; wh = ipw4[rq * 2 + 1];
        q4[i] = ipb[rq] + DOT4(xlo, wl) + DOT4(xhi, wh);
        wl = ipw4[rk * 2]; wh = ipw4[rk * 2 + 1];
        k4[i] = ipb[rk] + DOT4(xlo, wl) + DOT4(xhi, wh);
        wl = ipw4[rv * 2]; wh = ipw4[rv * 2 + 1];
        v4[i] = ipb[rv] + DOT4(xlo, wl) + DOT4(xhi, wh);
    }

    // ---- attention: 4 owned heads; kv packed f16 -> one gather per (h,j) ----
    int kvg[4][8];
    #pragma unroll
    for (int i = 0; i < 4; ++i) {
        half2v pk = __builtin_amdgcn_cvt_pkrtz(k4[i], v4[i]);
        int kvp = __builtin_bit_cast(int, pk);
        GATHERJ8(kvg[i], kvp);
    }
    float or4[4];
    #pragma unroll
    for (int i = 0; i < 4; ++i) {
        const float qh2 = q4[i] * 1.44269504f;   // log2(e) prefold
        float sum = 0.f, ov = 0.f;
        #pragma unroll
        for (int j = 0; j < 8; ++j) {
            half2v kv = __builtin_bit_cast(half2v, kvg[i][j]);
            float kf = (float)kv.x, vf = (float)kv.y;
            float pe = exp2f(qh2 * kf);
            sum += pe;
            ov = fmaf(pe, vf, ov);
        }
        or4[i] = ov * __builtin_amdgcn_rcpf(sum);
    }

    // ---- out_proj: own 4 rows; orow full via partner exchange ----
    float ooth[4] = {SWZ1(or4[0]), SWZ1(or4[1]), SWZ1(or4[2]), SWZ1(or4[3])};
    float olo[4], ohi[4];
    #pragma unroll
    for (int j = 0; j < 4; ++j) {
        olo[j] = sel ? or4[j] : ooth[j];
        ohi[j] = sel ? ooth[j] : or4[j];
    }
    const float4* opw4 = reinterpret_cast<const float4*>(opw);
    float ao4[4];
    #pragma unroll
    for (int i = 0; i < 4; ++i) {
        int r = e0 + i;
        float4 wl = opw4[r * 2], wh = opw4[r * 2 + 1];
        ao4[i] = opb[r] + DOT4(olo, wl) + DOT4(ohi, wh);
    }

    // ---- quantum ring: full c row locally -> full z locally ----
    float c4[4];
    #pragma unroll
    for (int i = 0; i < 4; ++i) c4[i] = __cosf(ao4[i] + rxa[e0 + i]);
    float coth[4] = {SWZ1(c4[0]), SWZ1(c4[1]), SWZ1(c4[2]), SWZ1(c4[3])};
    float cc[8];
    #pragma unroll
    for (int j = 0; j < 4; ++j) {
        cc[j]     = sel ? c4[j] : coth[j];
        cc[4 + j] = sel ? coth[j] : c4[j];
    }
    float z8[8];
    {
        float run = cc[0];
        #pragma unroll
        for (int w = 1; w < 8; ++w) { run *= cc[w]; z8[w] = run; }
        float s17 = cc[1];
        #pragma unroll
        for (int w = 2; w < 8; ++w) s17 *= cc[w];
        z8[0] = s17;
    }

    // ---- combine1 (z full per-lane) ----
    const float4* cw4 = reinterpret_cast<const float4*>(cw);
    float zlo[4] = {z8[0], z8[1], z8[2], z8[3]};
    float zhi[4] = {z8[4], z8[5], z8[6], z8[7]};
    float sa4[4];
    #pragma unroll
    for (int i = 0; i < 4; ++i) {
        int r = e0 + i;
        float4 wl = cw4[r * 2], wh = cw4[r * 2 + 1];
        sa4[i] = ao4[i] + cb[r] + DOT4(zlo, wl) + DOT4(zhi, wh);
    }
    // ---- combine2 (needs partner half of saq) ----
    float soth[4] = {SWZ1(sa4[0]), SWZ1(sa4[1]), SWZ1(sa4[2]), SWZ1(sa4[3])};
    float slo[4], shi[4];
    #pragma unroll
    for (int j = 0; j < 4; ++j) {
        slo[j] = sel ? sa4[j] : soth[j];
        shi[j] = sel ? soth[j] : sa4[j];
    }
    float at4[4];
    #pragma unroll
    for (int i = 0; i < 4; ++i) {
        int r = e0 + i;
        float4 wl = cw4[r * 2], wh = cw4[r * 2 + 1];
        at4[i] = cb[r] + DOT4(slo, wl) + DOT4(shi, wh);
    }

    // ---- LayerNorm1 over 8 (own 4 + partner) ----
    float r1[4];
    #pragma unroll
    for (int i = 0; i < 4; ++i) r1[i] = xown[i] + at4[i];
    float s4 = ((r1[0] + r1[1]) + (r1[2] + r1[3]));
    float mean = (s4 + SWZ1(s4)) * 0.125f;
    float dv[4];
    float vq = 0.f;
    #pragma unroll
    for (int i = 0; i < 4; ++i) { dv[i] = r1[i] - mean; vq = fmaf(dv[i], dv[i], vq); }
    float var = (vq + SWZ1(vq)) * 0.125f;
    float rs = __builtin_amdgcn_rsqf(var + 1e-5f);
    float4 hh4;
    hh4.x = fmaf(dv[0] * rs, g1[e0],     b1[e0]);
    hh4.y = fmaf(dv[1] * rs, g1[e0 + 1], b1[e0 + 1]);
    hh4.z = fmaf(dv[2] * rs, g1[e0 + 2], b1[e0 + 2]);
    hh4.w = fmaf(dv[3] * rs, g1[e0 + 3], b1[e0 + 3]);

    *reinterpret_cast<float4*>(hhout + base + e0) = hh4;
}

// ================= K2: FFN + LN2 (LDS-staged fragments) =================
// hh and out alias (both = d_out): no __restrict__ on them.
__global__ __launch_bounds__(256) void tbq_ffn(
    const float* hh,
    const float* __restrict__ rxf,
    const half4* __restrict__ a1ws, const half4* __restrict__ a2ws,
    const float* __restrict__ l2b,
    const float* __restrict__ g2,  const float* __restrict__ b2,
    float* out)
{
    __shared__ half4 a1l[2048];     // 16KB
    __shared__ half4 a2l[2048];     // 16KB

    const int tid = threadIdx.x;
    const int l   = tid & 63;
    const int wv  = tid >> 6;

    // ---- cooperative stage of prepacked fragments into LDS ----
    {
        const uint4* s1 = reinterpret_cast<const uint4*>(a1ws);
        const uint4* s2 = reinterpret_cast<const uint4*>(a2ws);
        uint4* t1 = reinterpret_cast<uint4*>(a1l);
        uint4* t2 = reinterpret_cast<uint4*>(a2l);
        #pragma unroll
        for (int i = 0; i < 4; ++i) {
            t1[tid + i * 256] = s1[tid + i * 256];
            t2[tid + i * 256] = s2[tid + i * 256];
        }
    }

    const int m  = l & 15;
    const int kg = (l >> 4) * 4;                    // 0,4,8,12
    const int tok0 = blockIdx.x * 128 + wv * 32;    // this wave's 32 tokens

    // ---- hh rows for bz build + epilogue (lanes 0-31) ----
    float4 h40 = make_float4(0.f, 0.f, 0.f, 0.f), h41 = h40;
    if (l < 32) {
        h40 = *reinterpret_cast<const float4*>(hh + (tok0 + m) * 8 + kg);
        h41 = *reinterpret_cast<const float4*>(hh + (tok0 + 16 + m) * 8 + kg);
    }

    // ---- bz fragments: zf = cos(hh + rxf); bias row k==8 = 1 ----
    const half4 zh = {(__fp16)0.f, (__fp16)0.f, (__fp16)0.f, (__fp16)0.f};
    half4 bz0 = zh, bz1 = zh;
    if (l < 32) {
        float4 rx4 = *reinterpret_cast<const float4*>(rxf + kg);
        float z00 = __cosf(h40.x + rx4.x), z01 = __cosf(h40.y + rx4.y);
        float z02 = __cosf(h40.z + rx4.z), z03 = __cosf(h40.w + rx4.w);
        float z10 = __cosf(h41.x + rx4.x), z11 = __cosf(h41.y + rx4.y);
        float z12 = __cosf(h41.z + rx4.z), z13 = __cosf(h41.w + rx4.w);
        half2v c0 = __builtin_amdgcn_cvt_pkrtz(z00, z01);
        half2v c1 = __builtin_amdgcn_cvt_pkrtz(z02, z03);
        bz0.x = c0.x; bz0.y = c0.y; bz0.z = c1.x; bz0.w = c1.y;
        half2v c2 = __builtin_amdgcn_cvt_pkrtz(z10, z11);
        half2v c3 = __builtin_amdgcn_cvt_pkrtz(z12, z13);
        bz1.x = c2.x; bz1.y = c2.y; bz1.z = c3.x; bz1.w = c3.y;
    } else if (l < 48) {
        bz0.x = (__fp16)1.f; bz1.x = (__fp16)1.f;
    }

    __syncthreads();

    // ---- FFN loop: fragments from LDS, 4 MFMA chains/iter ----
    const float4v zero4 = {0.f, 0.f, 0.f, 0.f};
    float4v acc0 = zero4, acc1 = zero4;
    #pragma unroll
    for (int nf = 0; nf < 32; ++nf) {
        half4 a1f = a1l[nf * 64 + l];
        half4 a2f = a2l[nf * 64 + l];
        float4v d0 = __builtin_amdgcn_mfma_f32_16x16x16f16(a1f, bz0, zero4, 0, 0, 0);
        float4v d1 = __builtin_amdgcn_mfma_f32_16x16x16f16(a1f, bz1, zero4, 0, 0, 0);
        d0.x = fmaxf(d0.x, 0.f); d0.y = fmaxf(d0.y, 0.f);
        d0.z = fmaxf(d0.z, 0.f); d0.w = fmaxf(d0.w, 0.f);
        d1.x = fmaxf(d1.x, 0.f); d1.y = fmaxf(d1.y, 0.f);
        d1.z = fmaxf(d1.z, 0.f); d1.w = fmaxf(d1.w, 0.f);
        half2v q00 = __builtin_amdgcn_cvt_pkrtz(d0.x, d0.y);
        half2v q01 = __builtin_amdgcn_cvt_pkrtz(d0.z, d0.w);
        half2v q10 = __builtin_amdgcn_cvt_pkrtz(d1.x, d1.y);
        half2v q11 = __builtin_amdgcn_cvt_pkrtz(d1.z, d1.w);
        half4 bu0; bu0.x = q00.x; bu0.y = q00.y; bu0.z = q01.x; bu0.w = q01.y;
        half4 bu1; bu1.x = q10.x; bu1.y = q10.y; bu1.z = q11.x; bu1.w = q11.y;
        acc0 = __builtin_amdgcn_mfma_f32_16x16x16f16(a2f, bu0, acc0, 0, 0, 0);
        acc1 = __builtin_amdgcn_mfma_f32_16x16x16f16(a2f, bu1, acc1, 0, 0, 0);
    }

    // ---- epilogue: residual + LN2 + store (lanes 0-31, both tiles) ----
    if (l < 32) {
        float4 lb4 = *reinterpret_cast<const float4*>(l2b + kg);
        float4 g4  = *reinterpret_cast<const float4*>(g2 + kg);
        float4 bb4 = *reinterpret_cast<const float4*>(b2 + kg);

        #pragma unroll
        for (int tt = 0; tt < 2; ++tt) {
            float4v acc = tt ? acc1 : acc0;
            float4 h4   = tt ? h41 : h40;
            float r2[4];
            r2[0] = h4.x + acc.x + lb4.x;
            r2[1] = h4.y + acc.y + lb4.y;
            r2[2] = h4.z + acc.z + lb4.z;
            r2[3] = h4.w + acc.w + lb4.w;
            float part = ((r2[0] + r2[1]) + (r2[2] + r2[3]));
            float mean2 = (part + SWZ16(part)) * 0.125f;
            float d0 = r2[0] - mean2, d1_ = r2[1] - mean2,
                  d2 = r2[2] - mean2, d3 = r2[3] - mean2;
            float vp = ((d0 * d0 + d1_ * d1_) + (d2 * d2 + d3 * d3));
            float rs2 = __builtin_amdgcn_rsqf((vp + SWZ16(vp)) * 0.125f + 1e-5f);
            float4 o;
            o.x = fmaf(d0 * rs2, g4.x, bb4.x);
            o.y = fmaf(d1_ * rs2, g4.y, bb4.y);
            o.z = fmaf(d2 * rs2, g4.z, bb4.z);
            o.w = fmaf(d3 * rs2, g4.w, bb4.w);
            *reinterpret_cast<float4*>(out + (tok0 + tt * 16 + m) * 8 + kg) = o;
        }
    }
}

extern "C" void kernel_launch(void* const* d_in, const int* in_sizes, int n_in,
                              void* d_out, int out_size, void* d_ws, size_t ws_size,
                              hipStream_t stream) {
    const float* x   = (const float*)d_in[0];
    const float* ipw = (const float*)d_in[1];
    const float* ipb = (const float*)d_in[2];
    const float* opw = (const float*)d_in[3];
    const float* opb = (const float*)d_in[4];
    const float* rxa = (const float*)d_in[5];
    const float* cw  = (const float*)d_in[6];
    const float* cb  = (const float*)d_in[7];
    const float* g1  = (const float*)d_in[8];
    const float* b1  = (const float*)d_in[9];
    const float* rxf = (const float*)d_in[10];
    const float* l1w = (const float*)d_in[11];
    const float* l1b = (const float*)d_in[12];
    const float* l2w = (const float*)d_in[13];
    const float* l2b = (const float*)d_in[14];
    const float* g2  = (const float*)d_in[15];
    const float* b2  = (const float*)d_in[16];
    float* out = (float*)d_out;

    half4* a1ws = (half4*)d_ws;                    // 16KB
    half4* a2ws = (half4*)((char*)d_ws + 16384);   // 16KB

    const int tokens = 16384 * 8;   // 131072

    // K1: 2-lane front (blocks 0-63 also pack fragments into d_ws)
    tbq_front<<<dim3(tokens / 32), dim3(64), 0, stream>>>(
        x, ipw, ipb, opw, opb, rxa, cw, cb, g1, b1,
        l1w, l1b, l2w, a1ws, a2ws, out);

    // K2: FFN + LN2; 4 waves/block, LDS-staged fragments
    tbq_ffn<<<dim3(tokens / 128), dim3(256), 0, stream>>>(
        out, rxf, a1ws, a2ws, l2b, g2, b2, out);
}

// Round 16
// 22.111 us; speedup vs baseline: 1.3328x; 1.3328x over previous
//
#include <hip/hip_runtime.h>

// TransformerBlockQuantum: B=16384, S=8, E=8, H=8 (dk=1), NW=8, FFN=512.
// R16: single fused kernel, 256 thr (4 waves) = 256 tokens per block.
//  1) cooperative pack: W1(+bias row)/W2 f32 -> f16 MFMA A-fragments direct
//     into LDS (loads issue at block start; latency hides under front)
//  2) front: 1 thread/token (R13-proven chain), hh -> LDS (no HBM roundtrip)
//  3) FFN: each wave does its own 64 tokens = 4 16x16 MFMA tiles, fragments
//     from LDS, 4 independent acc chains; residual+LN2+store.
// LDS: 16+16+12 = 44KB -> 3 blocks/CU = 12 waves/CU. 512 blocks. d_ws unused.

typedef __fp16 half2v __attribute__((ext_vector_type(2)));
typedef __fp16 half4  __attribute__((ext_vector_type(4)));
typedef float  float4v __attribute__((ext_vector_type(4)));

#define SWZ(v, J) __int_as_float(__builtin_amdgcn_ds_swizzle(__float_as_int(v), ((J) << 5) | 0x18))
#define SWZ16(v) __int_as_float(__builtin_amdgcn_ds_swizzle(__float_as_int(v), (16 << 10) | 0x1F))

__global__ __launch_bounds__(256, 3) void tbq_fused(
    const float* __restrict__ x,
    const float* __restrict__ ipw, const float* __restrict__ ipb,
    const float* __restrict__ opw, const float* __restrict__ opb,
    const float* __restrict__ rxa,
    const float* __restrict__ cw,  const float* __restrict__ cb,
    const float* __restrict__ g1,  const float* __restrict__ b1,
    const float* __restrict__ rxf,
    const float* __restrict__ l1w, const float* __restrict__ l1b,
    const float* __restrict__ l2w, const float* __restrict__ l2b,
    const float* __restrict__ g2,  const float* __restrict__ b2,
    float* __restrict__ out)
{
    __shared__ half4 a1l[2048];                       // 16KB
    __shared__ half4 a2l[2048];                       // 16KB
    __shared__ __align__(16) float lds_hh[256][12];   // 12KB (48B stride, aligned)

    const int tid = threadIdx.x;
    const int l   = tid & 63;
    const int wv  = tid >> 6;
    const int tok = blockIdx.x * 256 + tid;
    const int base = tok * 8;

    // ---- cooperative fragment pack: f32 weights -> f16 frags in LDS ----
    // frag u = nf*64 + ll; lane ll holds A[m=ll&15][k0=(ll>>4)*4 + j].
    // a1: f=nf*16+m; k<8 -> W1[f][k]; k==8 -> l1b[f]; else 0.
    // a2: m<8 -> W2[m][nf*16+k]; else 0.
    const half4 zh = {(__fp16)0.f, (__fp16)0.f, (__fp16)0.f, (__fp16)0.f};
    #pragma unroll
    for (int i = 0; i < 8; ++i) {
        const int u  = tid + i * 256;
        const int nf = u >> 6, ll = u & 63;
        const int mm = ll & 15, kk0 = (ll >> 4) * 4;
        half4 r1 = zh;
        if (ll < 32) {
            float4 w = *reinterpret_cast<const float4*>(l1w + (nf * 16 + mm) * 8 + kk0);
            half2v c0 = __builtin_amdgcn_cvt_pkrtz(w.x, w.y);
            half2v c1 = __builtin_amdgcn_cvt_pkrtz(w.z, w.w);
            r1.x = c0.x; r1.y = c0.y; r1.z = c1.x; r1.w = c1.y;
        } else if (ll < 48) {
            r1.x = (__fp16)l1b[nf * 16 + mm];
        }
        a1l[u] = r1;
        half4 r2 = zh;
        if (mm < 8) {
            float4 w = *reinterpret_cast<const float4*>(l2w + mm * 512 + nf * 16 + kk0);
            half2v c0 = __builtin_amdgcn_cvt_pkrtz(w.x, w.y);
            half2v c1 = __builtin_amdgcn_cvt_pkrtz(w.z, w.w);
            r2.x = c0.x; r2.y = c0.y; r2.z = c1.x; r2.w = c1.y;
        }
        a2l[u] = r2;
    }

    // ---- front: 1 thread per token (R13-proven) ----
    float xr[8];
    {
        const float4* px = reinterpret_cast<const float4*>(x + base);
        float4 a = px[0], b = px[1];
        xr[0] = a.x; xr[1] = a.y; xr[2] = a.z; xr[3] = a.w;
        xr[4] = b.x; xr[5] = b.y; xr[6] = b.z; xr[7] = b.w;
    }

    float q[8], k[8], v[8];
    #pragma unroll
    for (int e = 0; e < 8; ++e) {
        float aq = ipb[e], ak = ipb[8 + e], av = ipb[16 + e];
        #pragma unroll
        for (int d = 0; d < 8; ++d) {
            aq = fmaf(xr[d], ipw[e * 8 + d],       aq);
            ak = fmaf(xr[d], ipw[64 + e * 8 + d],  ak);
            av = fmaf(xr[d], ipw[128 + e * 8 + d], av);
        }
        q[e] = aq; k[e] = ak; v[e] = av;
    }

    // attention; softmax without max-subtraction (shift-invariant, |s| small)
    float orow[8];
    #pragma unroll
    for (int h = 0; h < 8; ++h) {
        const float kh = k[h], vh = v[h], qh = q[h];
        float kk[8], vv[8];
        kk[0] = SWZ(kh, 0); kk[1] = SWZ(kh, 1); kk[2] = SWZ(kh, 2); kk[3] = SWZ(kh, 3);
        kk[4] = SWZ(kh, 4); kk[5] = SWZ(kh, 5); kk[6] = SWZ(kh, 6); kk[7] = SWZ(kh, 7);
        vv[0] = SWZ(vh, 0); vv[1] = SWZ(vh, 1); vv[2] = SWZ(vh, 2); vv[3] = SWZ(vh, 3);
        vv[4] = SWZ(vh, 4); vv[5] = SWZ(vh, 5); vv[6] = SWZ(vh, 6); vv[7] = SWZ(vh, 7);
        float p[8];
        #pragma unroll
        for (int j = 0; j < 8; ++j) p[j] = __expf(qh * kk[j]);
        float sum = ((p[0] + p[1]) + (p[2] + p[3])) + ((p[4] + p[5]) + (p[6] + p[7]));
        float ov = 0.f;
        #pragma unroll
        for (int j = 0; j < 8; ++j) ov = fmaf(p[j], vv[j], ov);
        orow[h] = ov * __builtin_amdgcn_rcpf(sum);
    }

    float ao[8];
    #pragma unroll
    for (int e = 0; e < 8; ++e) {
        float t = opb[e];
        #pragma unroll
        for (int h = 0; h < 8; ++h) t = fmaf(orow[h], opw[e * 8 + h], t);
        ao[e] = t;
    }

    float c[8];
    #pragma unroll
    for (int w = 0; w < 8; ++w) c[w] = __cosf(ao[w] + rxa[w]);
    float z[8];
    {
        float run = c[0];
        #pragma unroll
        for (int w = 1; w < 8; ++w) { run *= c[w]; z[w] = run; }
        float s17 = c[1];
        #pragma unroll
        for (int w = 2; w < 8; ++w) s17 *= c[w];
        z[0] = s17;
    }

    float saq[8];
    #pragma unroll
    for (int e = 0; e < 8; ++e) {
        float t = cb[e];
        #pragma unroll
        for (int w = 0; w < 8; ++w) t = fmaf(z[w], cw[e * 8 + w], t);
        saq[e] = ao[e] + t;
    }
    float at[8];
    #pragma unroll
    for (int e = 0; e < 8; ++e) {
        float t = cb[e];
        #pragma unroll
        for (int w = 0; w < 8; ++w) t = fmaf(saq[w], cw[e * 8 + w], t);
        at[e] = t;
    }

    float r[8]; float mean = 0.f;
    #pragma unroll
    for (int e = 0; e < 8; ++e) { r[e] = xr[e] + at[e]; mean += r[e]; }
    mean *= 0.125f;
    float var = 0.f;
    #pragma unroll
    for (int e = 0; e < 8; ++e) { float d = r[e] - mean; var = fmaf(d, d, var); }
    var *= 0.125f;
    float rs = __builtin_amdgcn_rsqf(var + 1e-5f);
    {
        float4 hlo, hhi;
        hlo.x = fmaf((r[0] - mean) * rs, g1[0], b1[0]);
        hlo.y = fmaf((r[1] - mean) * rs, g1[1], b1[1]);
        hlo.z = fmaf((r[2] - mean) * rs, g1[2], b1[2]);
        hlo.w = fmaf((r[3] - mean) * rs, g1[3], b1[3]);
        hhi.x = fmaf((r[4] - mean) * rs, g1[4], b1[4]);
        hhi.y = fmaf((r[5] - mean) * rs, g1[5], b1[5]);
        hhi.z = fmaf((r[6] - mean) * rs, g1[6], b1[6]);
        hhi.w = fmaf((r[7] - mean) * rs, g1[7], b1[7]);
        *reinterpret_cast<float4*>(&lds_hh[tid][0]) = hlo;
        *reinterpret_cast<float4*>(&lds_hh[tid][4]) = hhi;
    }
    __syncthreads();

    // ---- FFN: wave wv handles its own 64 tokens = tiles 4wv..4wv+3 ----
    const int m  = l & 15;
    const int kg = (l >> 4) * 4;      // 0,4,8,12
    const int wtok = wv * 64;         // block-local first token of this wave

    float4 h40 = make_float4(0.f, 0.f, 0.f, 0.f), h41 = h40, h42 = h40, h43 = h40;
    half4 bz0 = zh, bz1 = zh, bz2 = zh, bz3 = zh;
    if (l < 32) {
        h40 = *reinterpret_cast<const float4*>(&lds_hh[wtok + m][kg]);
        h41 = *reinterpret_cast<const float4*>(&lds_hh[wtok + 16 + m][kg]);
        h42 = *reinterpret_cast<const float4*>(&lds_hh[wtok + 32 + m][kg]);
        h43 = *reinterpret_cast<const float4*>(&lds_hh[wtok + 48 + m][kg]);
        float4 rx4 = *reinterpret_cast<const float4*>(rxf + kg);
        half2v c0, c1;
        c0 = __builtin_amdgcn_cvt_pkrtz(__cosf(h40.x + rx4.x), __cosf(h40.y + rx4.y));
        c1 = __builtin_amdgcn_cvt_pkrtz(__cosf(h40.z + rx4.z), __cosf(h40.w + rx4.w));
        bz0.x = c0.x; bz0.y = c0.y; bz0.z = c1.x; bz0.w = c1.y;
        c0 = __builtin_amdgcn_cvt_pkrtz(__cosf(h41.x + rx4.x), __cosf(h41.y + rx4.y));
        c1 = __builtin_amdgcn_cvt_pkrtz(__cosf(h41.z + rx4.z), __cosf(h41.w + rx4.w));
        bz1.x = c0.x; bz1.y = c0.y; bz1.z = c1.x; bz1.w = c1.y;
        c0 = __builtin_amdgcn_cvt_pkrtz(__cosf(h42.x + rx4.x), __cosf(h42.y + rx4.y));
        c1 = __builtin_amdgcn_cvt_pkrtz(__cosf(h42.z + rx4.z), __cosf(h42.w + rx4.w));
        bz2.x = c0.x; bz2.y = c0.y; bz2.z = c1.x; bz2.w = c1.y;
        c0 = __builtin_amdgcn_cvt_pkrtz(__cosf(h43.x + rx4.x), __cosf(h43.y + rx4.y));
        c1 = __builtin_amdgcn_cvt_pkrtz(__cosf(h43.z + rx4.z), __cosf(h43.w + rx4.w));
        bz3.x = c0.x; bz3.y = c0.y; bz3.z = c1.x; bz3.w = c1.y;
    } else if (l < 48) {
        bz0.x = (__fp16)1.f; bz1.x = (__fp16)1.f;
        bz2.x = (__fp16)1.f; bz3.x = (__fp16)1.f;   // bias row k==8
    }

    const float4v zero4 = {0.f, 0.f, 0.f, 0.f};
    float4v acc0 = zero4, acc1 = zero4, acc2 = zero4, acc3 = zero4;
    #pragma unroll
    for (int nf = 0; nf < 32; ++nf) {
        half4 a1f = a1l[nf * 64 + l];
        half4 a2f = a2l[nf * 64 + l];
        float4v d0 = __builtin_amdgcn_mfma_f32_16x16x16f16(a1f, bz0, zero4, 0, 0, 0);
        float4v d1 = __builtin_amdgcn_mfma_f32_16x16x16f16(a1f, bz1, zero4, 0, 0, 0);
        float4v d2 = __builtin_amdgcn_mfma_f32_16x16x16f16(a1f, bz2, zero4, 0, 0, 0);
        float4v d3 = __builtin_amdgcn_mfma_f32_16x16x16f16(a1f, bz3, zero4, 0, 0, 0);
        d0.x = fmaxf(d0.x, 0.f); d0.y = fmaxf(d0.y, 0.f);
        d0.z = fmaxf(d0.z, 0.f); d0.w = fmaxf(d0.w, 0.f);
        d1.x = fmaxf(d1.x, 0.f); d1.y = fmaxf(d1.y, 0.f);
        d1.z = fmaxf(d1.z, 0.f); d1.w = fmaxf(d1.w, 0.f);
        d2.x = fmaxf(d2.x, 0.f); d2.y = fmaxf(d2.y, 0.f);
        d2.z = fmaxf(d2.z, 0.f); d2.w = fmaxf(d2.w, 0.f);
        d3.x = fmaxf(d3.x, 0.f); d3.y = fmaxf(d3.y, 0.f);
        d3.z = fmaxf(d3.z, 0.f); d3.w = fmaxf(d3.w, 0.f);
        half2v p0, p1;
        half4 bu;
        p0 = __builtin_amdgcn_cvt_pkrtz(d0.x, d0.y);
        p1 = __builtin_amdgcn_cvt_pkrtz(d0.z, d0.w);
        bu.x = p0.x; bu.y = p0.y; bu.z = p1.x; bu.w = p1.y;
        acc0 = __builtin_amdgcn_mfma_f32_16x16x16f16(a2f, bu, acc0, 0, 0, 0);
        p0 = __builtin_amdgcn_cvt_pkrtz(d1.x, d1.y);
        p1 = __builtin_amdgcn_cvt_pkrtz(d1.z, d1.w);
        bu.x = p0.x; bu.y = p0.y; bu.z = p1.x; bu.w = p1.y;
        acc1 = __builtin_amdgcn_mfma_f32_16x16x16f16(a2f, bu, acc1, 0, 0, 0);
        p0 = __builtin_amdgcn_cvt_pkrtz(d2.x, d2.y);
        p1 = __builtin_amdgcn_cvt_pkrtz(d2.z, d2.w);
        bu.x = p0.x; bu.y = p0.y; bu.z = p1.x; bu.w = p1.y;
        acc2 = __builtin_amdgcn_mfma_f32_16x16x16f16(a2f, bu, acc2, 0, 0, 0);
        p0 = __builtin_amdgcn_cvt_pkrtz(d3.x, d3.y);
        p1 = __builtin_amdgcn_cvt_pkrtz(d3.z, d3.w);
        bu.x = p0.x; bu.y = p0.y; bu.z = p1.x; bu.w = p1.y;
        acc3 = __builtin_amdgcn_mfma_f32_16x16x16f16(a2f, bu, acc3, 0, 0, 0);
    }

    // ---- epilogue: residual + LN2 + store (lanes 0-31, 4 tiles) ----
    if (l < 32) {
        const float4 lb4 = *reinterpret_cast<const float4*>(l2b + kg);
        const float4 g4  = *reinterpret_cast<const float4*>(g2 + kg);
        const float4 bb4 = *reinterpret_cast<const float4*>(b2 + kg);
        const int obase = blockIdx.x * 256 + wtok;

        #pragma unroll
        for (int tt = 0; tt < 4; ++tt) {
            float4v acc = (tt == 0) ? acc0 : (tt == 1) ? acc1 : (tt == 2) ? acc2 : acc3;
            float4 h4   = (tt == 0) ? h40  : (tt == 1) ? h41  : (tt == 2) ? h42  : h43;
            float r2[4];
            r2[0] = h4.x + acc.x + lb4.x;
            r2[1] = h4.y + acc.y + lb4.y;
            r2[2] = h4.z + acc.z + lb4.z;
            r2[3] = h4.w + acc.w + lb4.w;
            float part = ((r2[0] + r2[1]) + (r2[2] + r2[3]));
            float mean2 = (part + SWZ16(part)) * 0.125f;
            float d0 = r2[0] - mean2, d1_ = r2[1] - mean2,
                  d2 = r2[2] - mean2, d3 = r2[3] - mean2;
            float vp = ((d0 * d0 + d1_ * d1_) + (d2 * d2 + d3 * d3));
            float rs2 = __builtin_amdgcn_rsqf((vp + SWZ16(vp)) * 0.125f + 1e-5f);
            float4 o;
            o.x = fmaf(d0 * rs2, g4.x, bb4.x);
            o.y = fmaf(d1_ * rs2, g4.y, bb4.y);
            o.z = fmaf(d2 * rs2, g4.z, bb4.z);
            o.w = fmaf(d3 * rs2, g4.w, bb4.w);
            *reinterpret_cast<float4*>(out + (obase + tt * 16 + m) * 8 + kg) = o;
        }
    }
}

extern "C" void kernel_launch(void* const* d_in, const int* in_sizes, int n_in,
                              void* d_out, int out_size, void* d_ws, size_t ws_size,
                              hipStream_t stream) {
    const float* x   = (const float*)d_in[0];
    const float* ipw = (const float*)d_in[1];
    const float* ipb = (const float*)d_in[2];
    const float* opw = (const float*)d_in[3];
    const float* opb = (const float*)d_in[4];
    const float* rxa = (const float*)d_in[5];
    const float* cw  = (const float*)d_in[6];
    const float* cb  = (const float*)d_in[7];
    const float* g1  = (const float*)d_in[8];
    const float* b1  = (const float*)d_in[9];
    const float* rxf = (const float*)d_in[10];
    const float* l1w = (const float*)d_in[11];
    const float* l1b = (const float*)d_in[12];
    const float* l2w = (const float*)d_in[13];
    const float* l2b = (const float*)d_in[14];
    const float* g2  = (const float*)d_in[15];
    const float* b2  = (const float*)d_in[16];
    float* out = (float*)d_out;

    const int tokens = 16384 * 8;               // 131072
    tbq_fused<<<dim3(tokens / 256), dim3(256), 0, stream>>>(
        x, ipw, ipb, opw, opb, rxa, cw, cb, g1, b1, rxf,
        l1w, l1b, l2w, l2b, g2, b2, out);
}

// Round 17
// 20.740 us; speedup vs baseline: 1.4209x; 1.0661x over previous
//
#include <hip/hip_runtime.h>

// TransformerBlockQuantum: B=16384, S=8, E=8, H=8 (dk=1), NW=8, FFN=512.
// R17 = R16 + I$ shrink & scheduling freedom:
//  - FFN loop unroll 2, pack loop unroll 1 (code ~26KB -> ~14KB)
//  - launch_bounds(256,2) (grid-capped at 2 blocks/CU anyway; frees VGPRs)
//  - exp2 prefold in softmax; packed-f16 relu after cvt_pk
// Structure: 256 thr (4 waves) = 256 tokens/block; cooperative f32->f16
// fragment pack into LDS; 1-thread/token front; hh via LDS; per-wave 4 MFMA
// tile-pairs; residual+LN2+store. 512 blocks.

typedef __fp16 half2v __attribute__((ext_vector_type(2)));
typedef __fp16 half4  __attribute__((ext_vector_type(4)));
typedef float  float4v __attribute__((ext_vector_type(4)));

#define SWZ(v, J) __int_as_float(__builtin_amdgcn_ds_swizzle(__float_as_int(v), ((J) << 5) | 0x18))
#define SWZ16(v) __int_as_float(__builtin_amdgcn_ds_swizzle(__float_as_int(v), (16 << 10) | 0x1F))

__global__ __launch_bounds__(256, 2) void tbq_fused(
    const float* __restrict__ x,
    const float* __restrict__ ipw, const float* __restrict__ ipb,
    const float* __restrict__ opw, const float* __restrict__ opb,
    const float* __restrict__ rxa,
    const float* __restrict__ cw,  const float* __restrict__ cb,
    const float* __restrict__ g1,  const float* __restrict__ b1,
    const float* __restrict__ rxf,
    const float* __restrict__ l1w, const float* __restrict__ l1b,
    const float* __restrict__ l2w, const float* __restrict__ l2b,
    const float* __restrict__ g2,  const float* __restrict__ b2,
    float* __restrict__ out)
{
    __shared__ half4 a1l[2048];                       // 16KB
    __shared__ half4 a2l[2048];                       // 16KB
    __shared__ __align__(16) float lds_hh[256][12];   // 12KB

    const int tid = threadIdx.x;
    const int l   = tid & 63;
    const int wv  = tid >> 6;
    const int tok = blockIdx.x * 256 + tid;
    const int base = tok * 8;

    // ---- cooperative fragment pack: f32 weights -> f16 frags in LDS ----
    const half4 zh = {(__fp16)0.f, (__fp16)0.f, (__fp16)0.f, (__fp16)0.f};
    #pragma unroll 1
    for (int i = 0; i < 8; ++i) {
        const int u  = tid + i * 256;
        const int nf = u >> 6, ll = u & 63;
        const int mm = ll & 15, kk0 = (ll >> 4) * 4;
        half4 r1 = zh;
        if (ll < 32) {
            float4 w = *reinterpret_cast<const float4*>(l1w + (nf * 16 + mm) * 8 + kk0);
            half2v c0 = __builtin_amdgcn_cvt_pkrtz(w.x, w.y);
            half2v c1 = __builtin_amdgcn_cvt_pkrtz(w.z, w.w);
            r1.x = c0.x; r1.y = c0.y; r1.z = c1.x; r1.w = c1.y;
        } else if (ll < 48) {
            r1.x = (__fp16)l1b[nf * 16 + mm];
        }
        a1l[u] = r1;
        half4 r2 = zh;
        if (mm < 8) {
            float4 w = *reinterpret_cast<const float4*>(l2w + mm * 512 + nf * 16 + kk0);
            half2v c0 = __builtin_amdgcn_cvt_pkrtz(w.x, w.y);
            half2v c1 = __builtin_amdgcn_cvt_pkrtz(w.z, w.w);
            r2.x = c0.x; r2.y = c0.y; r2.z = c1.x; r2.w = c1.y;
        }
        a2l[u] = r2;
    }

    // ---- front: 1 thread per token ----
    float xr[8];
    {
        const float4* px = reinterpret_cast<const float4*>(x + base);
        float4 a = px[0], b = px[1];
        xr[0] = a.x; xr[1] = a.y; xr[2] = a.z; xr[3] = a.w;
        xr[4] = b.x; xr[5] = b.y; xr[6] = b.z; xr[7] = b.w;
    }

    float q[8], k[8], v[8];
    #pragma unroll
    for (int e = 0; e < 8; ++e) {
        float aq = ipb[e], ak = ipb[8 + e], av = ipb[16 + e];
        #pragma unroll
        for (int d = 0; d < 8; ++d) {
            aq = fmaf(xr[d], ipw[e * 8 + d],       aq);
            ak = fmaf(xr[d], ipw[64 + e * 8 + d],  ak);
            av = fmaf(xr[d], ipw[128 + e * 8 + d], av);
        }
        q[e] = aq; k[e] = ak; v[e] = av;
    }

    // attention; softmax without max-subtraction; exp2 prefold
    float orow[8];
    #pragma unroll
    for (int h = 0; h < 8; ++h) {
        const float kh = k[h], vh = v[h];
        const float qh2 = q[h] * 1.44269504f;
        float kk[8], vv[8];
        kk[0] = SWZ(kh, 0); kk[1] = SWZ(kh, 1); kk[2] = SWZ(kh, 2); kk[3] = SWZ(kh, 3);
        kk[4] = SWZ(kh, 4); kk[5] = SWZ(kh, 5); kk[6] = SWZ(kh, 6); kk[7] = SWZ(kh, 7);
        vv[0] = SWZ(vh, 0); vv[1] = SWZ(vh, 1); vv[2] = SWZ(vh, 2); vv[3] = SWZ(vh, 3);
        vv[4] = SWZ(vh, 4); vv[5] = SWZ(vh, 5); vv[6] = SWZ(vh, 6); vv[7] = SWZ(vh, 7);
        float p[8];
        #pragma unroll
        for (int j = 0; j < 8; ++j) p[j] = exp2f(qh2 * kk[j]);
        float sum = ((p[0] + p[1]) + (p[2] + p[3])) + ((p[4] + p[5]) + (p[6] + p[7]));
        float ov = 0.f;
        #pragma unroll
        for (int j = 0; j < 8; ++j) ov = fmaf(p[j], vv[j], ov);
        orow[h] = ov * __builtin_amdgcn_rcpf(sum);
    }

    float ao[8];
    #pragma unroll
    for (int e = 0; e < 8; ++e) {
        float t = opb[e];
        #pragma unroll
        for (int h = 0; h < 8; ++h) t = fmaf(orow[h], opw[e * 8 + h], t);
        ao[e] = t;
    }

    float c[8];
    #pragma unroll
    for (int w = 0; w < 8; ++w) c[w] = __cosf(ao[w] + rxa[w]);
    float z[8];
    {
        float run = c[0];
        #pragma unroll
        for (int w = 1; w < 8; ++w) { run *= c[w]; z[w] = run; }
        float s17 = c[1];
        #pragma unroll
        for (int w = 2; w < 8; ++w) s17 *= c[w];
        z[0] = s17;
    }

    float saq[8];
    #pragma unroll
    for (int e = 0; e < 8; ++e) {
        float t = cb[e];
        #pragma unroll
        for (int w = 0; w < 8; ++w) t = fmaf(z[w], cw[e * 8 + w], t);
        saq[e] = ao[e] + t;
    }
    float at[8];
    #pragma unroll
    for (int e = 0; e < 8; ++e) {
        float t = cb[e];
        #pragma unroll
        for (int w = 0; w < 8; ++w) t = fmaf(saq[w], cw[e * 8 + w], t);
        at[e] = t;
    }

    float r[8]; float mean = 0.f;
    #pragma unroll
    for (int e = 0; e < 8; ++e) { r[e] = xr[e] + at[e]; mean += r[e]; }
    mean *= 0.125f;
    float var = 0.f;
    #pragma unroll
    for (int e = 0; e < 8; ++e) { float d = r[e] - mean; var = fmaf(d, d, var); }
    var *= 0.125f;
    float rs = __builtin_amdgcn_rsqf(var + 1e-5f);
    {
        float4 hlo, hhi;
        hlo.x = fmaf((r[0] - mean) * rs, g1[0], b1[0]);
        hlo.y = fmaf((r[1] - mean) * rs, g1[1], b1[1]);
        hlo.z = fmaf((r[2] - mean) * rs, g1[2], b1[2]);
        hlo.w = fmaf((r[3] - mean) * rs, g1[3], b1[3]);
        hhi.x = fmaf((r[4] - mean) * rs, g1[4], b1[4]);
        hhi.y = fmaf((r[5] - mean) * rs, g1[5], b1[5]);
        hhi.z = fmaf((r[6] - mean) * rs, g1[6], b1[6]);
        hhi.w = fmaf((r[7] - mean) * rs, g1[7], b1[7]);
        *reinterpret_cast<float4*>(&lds_hh[tid][0]) = hlo;
        *reinterpret_cast<float4*>(&lds_hh[tid][4]) = hhi;
    }
    __syncthreads();

    // ---- FFN: wave wv handles its own 64 tokens = 4 tiles ----
    const int m  = l & 15;
    const int kg = (l >> 4) * 4;
    const int wtok = wv * 64;

    float4 h40 = make_float4(0.f, 0.f, 0.f, 0.f), h41 = h40, h42 = h40, h43 = h40;
    half4 bz0 = zh, bz1 = zh, bz2 = zh, bz3 = zh;
    if (l < 32) {
        h40 = *reinterpret_cast<const float4*>(&lds_hh[wtok + m][kg]);
        h41 = *reinterpret_cast<const float4*>(&lds_hh[wtok + 16 + m][kg]);
        h42 = *reinterpret_cast<const float4*>(&lds_hh[wtok + 32 + m][kg]);
        h43 = *reinterpret_cast<const float4*>(&lds_hh[wtok + 48 + m][kg]);
        float4 rx4 = *reinterpret_cast<const float4*>(rxf + kg);
        half2v c0, c1;
        c0 = __builtin_amdgcn_cvt_pkrtz(__cosf(h40.x + rx4.x), __cosf(h40.y + rx4.y));
        c1 = __builtin_amdgcn_cvt_pkrtz(__cosf(h40.z + rx4.z), __cosf(h40.w + rx4.w));
        bz0.x = c0.x; bz0.y = c0.y; bz0.z = c1.x; bz0.w = c1.y;
        c0 = __builtin_amdgcn_cvt_pkrtz(__cosf(h41.x + rx4.x), __cosf(h41.y + rx4.y));
        c1 = __builtin_amdgcn_cvt_pkrtz(__cosf(h41.z + rx4.z), __cosf(h41.w + rx4.w));
        bz1.x = c0.x; bz1.y = c0.y; bz1.z = c1.x; bz1.w = c1.y;
        c0 = __builtin_amdgcn_cvt_pkrtz(__cosf(h42.x + rx4.x), __cosf(h42.y + rx4.y));
        c1 = __builtin_amdgcn_cvt_pkrtz(__cosf(h42.z + rx4.z), __cosf(h42.w + rx4.w));
        bz2.x = c0.x; bz2.y = c0.y; bz2.z = c1.x; bz2.w = c1.y;
        c0 = __builtin_amdgcn_cvt_pkrtz(__cosf(h43.x + rx4.x), __cosf(h43.y + rx4.y));
        c1 = __builtin_amdgcn_cvt_pkrtz(__cosf(h43.z + rx4.z), __cosf(h43.w + rx4.w));
        bz3.x = c0.x; bz3.y = c0.y; bz3.z = c1.x; bz3.w = c1.y;
    } else if (l < 48) {
        bz0.x = (__fp16)1.f; bz1.x = (__fp16)1.f;
        bz2.x = (__fp16)1.f; bz3.x = (__fp16)1.f;
    }

    const float4v zero4 = {0.f, 0.f, 0.f, 0.f};
    float4v acc0 = zero4, acc1 = zero4, acc2 = zero4, acc3 = zero4;
    #pragma unroll 2
    for (int nf = 0; nf < 32; ++nf) {
        half4 a1f = a1l[nf * 64 + l];
        half4 a2f = a2l[nf * 64 + l];
        float4v d0 = __builtin_amdgcn_mfma_f32_16x16x16f16(a1f, bz0, zero4, 0, 0, 0);
        float4v d1 = __builtin_amdgcn_mfma_f32_16x16x16f16(a1f, bz1, zero4, 0, 0, 0);
        float4v d2 = __builtin_amdgcn_mfma_f32_16x16x16f16(a1f, bz2, zero4, 0, 0, 0);
        float4v d3 = __builtin_amdgcn_mfma_f32_16x16x16f16(a1f, bz3, zero4, 0, 0, 0);
        // cvt first, relu as packed-f16 max (sign-preserving, equivalent)
        half4 bu0, bu1, bu2, bu3;
        {
            half2v p0 = __builtin_amdgcn_cvt_pkrtz(d0.x, d0.y);
            half2v p1 = __builtin_amdgcn_cvt_pkrtz(d0.z, d0.w);
            bu0.x = p0.x; bu0.y = p0.y; bu0.z = p1.x; bu0.w = p1.y;
            p0 = __builtin_amdgcn_cvt_pkrtz(d1.x, d1.y);
            p1 = __builtin_amdgcn_cvt_pkrtz(d1.z, d1.w);
            bu1.x = p0.x; bu1.y = p0.y; bu1.z = p1.x; bu1.w = p1.y;
            p0 = __builtin_amdgcn_cvt_pkrtz(d2.x, d2.y);
            p1 = __builtin_amdgcn_cvt_pkrtz(d2.z, d2.w);
            bu2.x = p0.x; bu2.y = p0.y; bu2.z = p1.x; bu2.w = p1.y;
            p0 = __builtin_amdgcn_cvt_pkrtz(d3.x, d3.y);
            p1 = __builtin_amdgcn_cvt_pkrtz(d3.z, d3.w);
            bu3.x = p0.x; bu3.y = p0.y; bu3.z = p1.x; bu3.w = p1.y;
        }
        bu0 = __builtin_elementwise_max(bu0, zh);
        bu1 = __builtin_elementwise_max(bu1, zh);
        bu2 = __builtin_elementwise_max(bu2, zh);
        bu3 = __builtin_elementwise_max(bu3, zh);
        acc0 = __builtin_amdgcn_mfma_f32_16x16x16f16(a2f, bu0, acc0, 0, 0, 0);
        acc1 = __builtin_amdgcn_mfma_f32_16x16x16f16(a2f, bu1, acc1, 0, 0, 0);
        acc2 = __builtin_amdgcn_mfma_f32_16x16x16f16(a2f, bu2, acc2, 0, 0, 0);
        acc3 = __builtin_amdgcn_mfma_f32_16x16x16f16(a2f, bu3, acc3, 0, 0, 0);
    }

    // ---- epilogue: residual + LN2 + store (lanes 0-31, 4 tiles) ----
    if (l < 32) {
        const float4 lb4 = *reinterpret_cast<const float4*>(l2b + kg);
        const float4 g4  = *reinterpret_cast<const float4*>(g2 + kg);
        const float4 bb4 = *reinterpret_cast<const float4*>(b2 + kg);
        const int obase = blockIdx.x * 256 + wtok;

        #pragma unroll
        for (int tt = 0; tt < 4; ++tt) {
            float4v acc = (tt == 0) ? acc0 : (tt == 1) ? acc1 : (tt == 2) ? acc2 : acc3;
            float4 h4   = (tt == 0) ? h40  : (tt == 1) ? h41  : (tt == 2) ? h42  : h43;
            float r2[4];
            r2[0] = h4.x + acc.x + lb4.x;
            r2[1] = h4.y + acc.y + lb4.y;
            r2[2] = h4.z + acc.z + lb4.z;
            r2[3] = h4.w + acc.w + lb4.w;
            float part = ((r2[0] + r2[1]) + (r2[2] + r2[3]));
            float mean2 = (part + SWZ16(part)) * 0.125f;
            float d0 = r2[0] - mean2, d1_ = r2[1] - mean2,
                  d2 = r2[2] - mean2, d3 = r2[3] - mean2;
            float vp = ((d0 * d0 + d1_ * d1_) + (d2 * d2 + d3 * d3));
            float rs2 = __builtin_amdgcn_rsqf((vp + SWZ16(vp)) * 0.125f + 1e-5f);
            float4 o;
            o.x = fmaf(d0 * rs2, g4.x, bb4.x);
            o.y = fmaf(d1_ * rs2, g4.y, bb4.y);
            o.z = fmaf(d2 * rs2, g4.z, bb4.z);
            o.w = fmaf(d3 * rs2, g4.w, bb4.w);
            *reinterpret_cast<float4*>(out + (obase + tt * 16 + m) * 8 + kg) = o;
        }
    }
}

extern "C" void kernel_launch(void* const* d_in, const int* in_sizes, int n_in,
                              void* d_out, int out_size, void* d_ws, size_t ws_size,
                              hipStream_t stream) {
    const float* x   = (const float*)d_in[0];
    const float* ipw = (const float*)d_in[1];
    const float* ipb = (const float*)d_in[2];
    const float* opw = (const float*)d_in[3];
    const float* opb = (const float*)d_in[4];
    const float* rxa = (const float*)d_in[5];
    const float* cw  = (const float*)d_in[6];
    const float* cb  = (const float*)d_in[7];
    const float* g1  = (const float*)d_in[8];
    const float* b1  = (const float*)d_in[9];
    const float* rxf = (const float*)d_in[10];
    const float* l1w = (const float*)d_in[11];
    const float* l1b = (const float*)d_in[12];
    const float* l2w = (const float*)d_in[13];
    const float* l2b = (const float*)d_in[14];
    const float* g2  = (const float*)d_in[15];
    const float* b2  = (const float*)d_in[16];
    float* out = (float*)d_out;

    const int tokens = 16384 * 8;               // 131072
    tbq_fused<<<dim3(tokens / 256), dim3(256), 0, stream>>>(
        x, ipw, ipb, opw, opb, rxa, cw, cb, g1, b1, rxf,
        l1w, l1b, l2w, l2b, g2, b2, out);
}